// Round 3
// baseline (1478.592 us; speedup 1.0000x reference)
//
#include <hip/hip_runtime.h>
#include <stdint.h>

// ---------------------------------------------------------------------------
// DiffTransformerLayer on MI355X (gfx950). ALL float I/O is FLOAT32 (per the
// harness contract: dtypes follow the reference, which is jnp.float32).
// Outputs (f32, concat): r2 [4,1024,1024], A [16,4,1024,1024].
// Internal GEMMs: bf16 MFMA 16x16x32, f32 accumulate.
// Workspace peak: 48 MB. Vt scratch lives in d_out's r2 region (written last).
// ---------------------------------------------------------------------------

typedef unsigned short u16;
typedef __attribute__((ext_vector_type(4))) float   floatx4;
typedef __attribute__((ext_vector_type(8))) __bf16  bf16x8;

#define LAMBDA_INIT_F 0.35550906759096926f
#define ONE_MINUS_LI  0.6444909324090307f

#define FLAG_OUT_BF16 1
#define FLAG_RELU     2
#define FLAG_BIAS     4
#define FLAG_SCALE    8
#define FLAG_MASK     16
#define FLAG_ACCUM    32
#define FLAG_BIAS_ROW 64
#define FLAG_LNH      128

__device__ __forceinline__ float bf2f(u16 u) {
    union { unsigned int i; float f; } w; w.i = ((unsigned int)u) << 16; return w.f;
}
__device__ __forceinline__ u16 f2bf(float f) {
    union { float f; unsigned int i; } w; w.f = f;
    unsigned int x = w.i;
    unsigned int r = x + 0x7fffu + ((x >> 16) & 1u);   // RNE
    return (u16)(r >> 16);
}
__device__ __forceinline__ float wred_sum(float v) {
#pragma unroll
    for (int off = 32; off > 0; off >>= 1) v += __shfl_xor(v, off, 64);
    return v;
}
__device__ __forceinline__ float wred_max(float v) {
#pragma unroll
    for (int off = 32; off > 0; off >>= 1) v = fmaxf(v, __shfl_xor(v, off, 64));
    return v;
}

// ---------------------------------------------------------------------------
// Batched GEMM: C[m][n] = epilogue( sum_k A[m][k]*B[n][k] )
// A: [M][K] (lda), B: [N][K] (ldb, i.e. B-transposed form). AF32/BF32 select
// f32 (converted to bf16 during staging) vs bf16 operand storage.
// Batch z = hz*nb + bz with independent element strides.
// Tile 128x128, BK=32, 256 threads (2x2 waves, 4x4 16x16x32 mfma frags).
// FLAG_LNH: grid.x==1, N==128: fused per-row LayerNorm over the 128 cols,
//           *(1-LAMBDA_INIT), bf16 store.
// ---------------------------------------------------------------------------
template <int FLAGS, int AF32, int BF32>
__global__ __launch_bounds__(256) void gemm_bt(
    const void* __restrict__ Ap, long long lda, long long sAh, long long sAb,
    const void* __restrict__ Bp, long long ldb, long long sBh, long long sBb,
    void* __restrict__ C, long long ldc, long long sCh, long long sCb,
    int K, int nb, float scale,
    const float* __restrict__ biasA, const float* __restrict__ biasB,
    int biasSplit, int biasRowStride,
    const int* __restrict__ mask, int maskS,
    const float* __restrict__ lnw, const float* __restrict__ lnb)
{
    const int z  = blockIdx.z;
    const int hz = z / nb, bz = z % nb;
    const long long aoff = hz * sAh + bz * sAb;
    const long long boff = hz * sBh + bz * sBb;
    const long long coff = hz * sCh + bz * sCb;

    __shared__ __attribute__((aligned(16))) u16 As[128 * 40];  // BK=32 +8 pad
    __shared__ __attribute__((aligned(16))) u16 Bs[128 * 40];

    const int tid  = threadIdx.x;
    const int lane = tid & 63;
    const int wid  = tid >> 6;
    const int wm   = wid >> 1, wn = wid & 1;
    const int m0   = blockIdx.y * 128;
    const int n0   = blockIdx.x * 128;
    const int sr   = tid >> 1;         // staging row 0..127
    const int sc   = (tid & 1) * 16;   // staging col 0/16

    floatx4 acc[4][4];
#pragma unroll
    for (int i = 0; i < 4; i++)
#pragma unroll
        for (int j = 0; j < 4; j++) acc[i][j] = (floatx4){0.f, 0.f, 0.f, 0.f};

    const int lr = lane & 15;  // frag row (A) / col (B)
    const int q  = lane >> 4;  // k-quad

    for (int k0 = 0; k0 < K; k0 += 32) {
        u16 ta[16], tb[16];
        if constexpr (AF32) {
            const float* ga = (const float*)Ap + aoff + (long long)(m0 + sr) * lda + (k0 + sc);
            float4 f0 = *(const float4*)(ga);
            float4 f1 = *(const float4*)(ga + 4);
            float4 f2 = *(const float4*)(ga + 8);
            float4 f3 = *(const float4*)(ga + 12);
            ta[0]=f2bf(f0.x); ta[1]=f2bf(f0.y); ta[2]=f2bf(f0.z); ta[3]=f2bf(f0.w);
            ta[4]=f2bf(f1.x); ta[5]=f2bf(f1.y); ta[6]=f2bf(f1.z); ta[7]=f2bf(f1.w);
            ta[8]=f2bf(f2.x); ta[9]=f2bf(f2.y); ta[10]=f2bf(f2.z); ta[11]=f2bf(f2.w);
            ta[12]=f2bf(f3.x); ta[13]=f2bf(f3.y); ta[14]=f2bf(f3.z); ta[15]=f2bf(f3.w);
        } else {
            const u16* ga = (const u16*)Ap + aoff + (long long)(m0 + sr) * lda + (k0 + sc);
            *(uint4*)&ta[0] = *(const uint4*)(ga);
            *(uint4*)&ta[8] = *(const uint4*)(ga + 8);
        }
        if constexpr (BF32) {
            const float* gb = (const float*)Bp + boff + (long long)(n0 + sr) * ldb + (k0 + sc);
            float4 f0 = *(const float4*)(gb);
            float4 f1 = *(const float4*)(gb + 4);
            float4 f2 = *(const float4*)(gb + 8);
            float4 f3 = *(const float4*)(gb + 12);
            tb[0]=f2bf(f0.x); tb[1]=f2bf(f0.y); tb[2]=f2bf(f0.z); tb[3]=f2bf(f0.w);
            tb[4]=f2bf(f1.x); tb[5]=f2bf(f1.y); tb[6]=f2bf(f1.z); tb[7]=f2bf(f1.w);
            tb[8]=f2bf(f2.x); tb[9]=f2bf(f2.y); tb[10]=f2bf(f2.z); tb[11]=f2bf(f2.w);
            tb[12]=f2bf(f3.x); tb[13]=f2bf(f3.y); tb[14]=f2bf(f3.z); tb[15]=f2bf(f3.w);
        } else {
            const u16* gb = (const u16*)Bp + boff + (long long)(n0 + sr) * ldb + (k0 + sc);
            *(uint4*)&tb[0] = *(const uint4*)(gb);
            *(uint4*)&tb[8] = *(const uint4*)(gb + 8);
        }
        __syncthreads();
        *(uint4*)&As[sr * 40 + sc]     = *(uint4*)&ta[0];
        *(uint4*)&As[sr * 40 + sc + 8] = *(uint4*)&ta[8];
        *(uint4*)&Bs[sr * 40 + sc]     = *(uint4*)&tb[0];
        *(uint4*)&Bs[sr * 40 + sc + 8] = *(uint4*)&tb[8];
        __syncthreads();

        bf16x8 af[4], bfr[4];
#pragma unroll
        for (int i = 0; i < 4; i++) {
            union { uint4 u; bf16x8 v; } t;
            t.u = *(const uint4*)&As[(wm * 64 + i * 16 + lr) * 40 + q * 8];
            af[i] = t.v;
        }
#pragma unroll
        for (int j = 0; j < 4; j++) {
            union { uint4 u; bf16x8 v; } t;
            t.u = *(const uint4*)&Bs[(wn * 64 + j * 16 + lr) * 40 + q * 8];
            bfr[j] = t.v;
        }
#pragma unroll
        for (int i = 0; i < 4; i++)
#pragma unroll
            for (int j = 0; j < 4; j++)
                acc[i][j] = __builtin_amdgcn_mfma_f32_16x16x32_bf16(af[i], bfr[j], acc[i][j], 0, 0, 0);
    }

    // C/D layout: row = (lane>>4)*4 + r, col = lane&15 (m89-verified)
    const int rq = lane >> 4;
    const int cc = lane & 15;

    if constexpr (FLAGS & FLAG_LNH) {
        __shared__ float lnred[2][128][2];
        float s_[4][4], q_[4][4];
#pragma unroll
        for (int i = 0; i < 4; i++)
#pragma unroll
            for (int r = 0; r < 4; r++) {
                float s = 0.f, qq = 0.f;
#pragma unroll
                for (int j = 0; j < 4; j++) { float v = acc[i][j][r]; s += v; qq += v * v; }
                s_[i][r] = s; q_[i][r] = qq;
            }
#pragma unroll
        for (int off = 1; off < 16; off <<= 1)
#pragma unroll
            for (int i = 0; i < 4; i++)
#pragma unroll
                for (int r = 0; r < 4; r++) {
                    s_[i][r] += __shfl_xor(s_[i][r], off, 64);
                    q_[i][r] += __shfl_xor(q_[i][r], off, 64);
                }
        if (cc == 0) {
#pragma unroll
            for (int i = 0; i < 4; i++)
#pragma unroll
                for (int r = 0; r < 4; r++) {
                    const int row = wm * 64 + i * 16 + rq * 4 + r;
                    lnred[wn][row][0] = s_[i][r];
                    lnred[wn][row][1] = q_[i][r];
                }
        }
        __syncthreads();
#pragma unroll
        for (int i = 0; i < 4; i++)
#pragma unroll
            for (int r = 0; r < 4; r++) {
                const int row = wm * 64 + i * 16 + rq * 4 + r;
                const float sum = lnred[0][row][0] + lnred[1][row][0];
                const float sq  = lnred[0][row][1] + lnred[1][row][1];
                const float mu  = sum * (1.f / 128.f);
                const float var = sq * (1.f / 128.f) - mu * mu;
                const float inv = rsqrtf(var + 1e-5f);
#pragma unroll
                for (int j = 0; j < 4; j++) {
                    const int col = wn * 64 + j * 16 + cc;
                    const float v = ((acc[i][j][r] - mu) * inv * lnw[col] + lnb[col]) * ONE_MINUS_LI;
                    ((u16*)C)[coff + (long long)(m0 + row) * ldc + col] = f2bf(v);
                }
            }
        return;
    }

#pragma unroll
    for (int j = 0; j < 4; j++) {
        const int col = n0 + wn * 64 + j * 16 + cc;
        float cbv = 0.f;
        if constexpr (FLAGS & FLAG_BIAS)
            cbv = (col < biasSplit) ? biasA[col] : biasB[col - biasSplit];
        bool keep = true;
        if constexpr (FLAGS & FLAG_MASK) keep = (mask[bz * maskS + col] != 0);
#pragma unroll
        for (int i = 0; i < 4; i++) {
#pragma unroll
            for (int r = 0; r < 4; r++) {
                const int row = m0 + wm * 64 + i * 16 + rq * 4 + r;
                float v = acc[i][j][r];
                if constexpr (FLAGS & FLAG_SCALE) v *= scale;
                float bv = cbv;
                if constexpr (FLAGS & FLAG_BIAS_ROW) bv = biasA[hz * biasRowStride + row];
                v += bv;
                if constexpr (FLAGS & FLAG_RELU) v = fmaxf(v, 0.f);
                if constexpr (FLAGS & FLAG_MASK) { if (!keep) v = -__builtin_inff(); }
                const long long idx = coff + (long long)row * ldc + col;
                if constexpr (FLAGS & FLAG_OUT_BF16) {
                    ((u16*)C)[idx] = f2bf(v);
                } else {
                    float* Cf = (float*)C;
                    if constexpr (FLAGS & FLAG_ACCUM) v += Cf[idx];
                    Cf[idx] = v;
                }
            }
        }
    }
}

// ---------------------------------------------------------------------------
// Pack kernels (f32 in -> bf16 out)
// ---------------------------------------------------------------------------
// WqkT [2048 n][1024 k]: n<1024 -> WQ1[h=n>>6][k][e=n&63]; else WK1
__global__ void pack_wqkt(const float* __restrict__ WQ, const float* __restrict__ WK,
                          u16* __restrict__ dst)
{
    int i = blockIdx.x * 256 + threadIdx.x;  // 2M
    int k = i & 1023;
    int n = i >> 10;
    float v;
    if (n < 1024) {
        int h = n >> 6, e = n & 63;
        v = WQ[(h * 1024 + k) * 64 + e];
    } else {
        int m = n - 1024; int h = m >> 6, e = m & 63;
        v = WK[(h * 1024 + k) * 64 + e];
    }
    dst[i] = f2bf(v);
}

// WvT [16 h][128 v][1024 d] = WV[h][d][v]
__global__ void pack_wvt(const float* __restrict__ WV, u16* __restrict__ dst)
{
    int i = blockIdx.x * 256 + threadIdx.x;  // 2M
    int d = i & 1023;
    int v = (i >> 10) & 127;
    int h = i >> 17;
    dst[i] = f2bf(WV[(h * 1024 + d) * 128 + v]);
}

// dst[C][R] = bf16(src[R][C]), R = 1<<rlog2
__global__ void transpose_bf(const float* __restrict__ src, u16* __restrict__ dst,
                             int rlog2, int C)
{
    long long i = (long long)blockIdx.x * 256 + threadIdx.x;
    int r = (int)(i & ((1 << rlog2) - 1));
    int c = (int)(i >> rlog2);
    dst[i] = f2bf(src[(long long)r * C + c]);
}

// In-place f32 row softmax over A region (65536 rows x 1024), * (1-lam);
// lam computed inline per wave (deterministic, identical everywhere).
__global__ __launch_bounds__(256) void softmax_rows(
    float* __restrict__ Aout,
    const float* __restrict__ lq1, const float* __restrict__ lk1,
    const float* __restrict__ lq2, const float* __restrict__ lk2)
{
    const int row  = blockIdx.x * 4 + (threadIdx.x >> 6);
    const int lane = threadIdx.x & 63;

    float d1 = lq1[lane] * lk1[lane];
    float d2 = lq2[lane] * lk2[lane];
    d1 = wred_sum(d1);
    d2 = wred_sum(d2);
    const float lamscale = 1.f - (expf(d1) - expf(d2) + LAMBDA_INIT_F);

    float* p = Aout + (long long)row * 1024 + lane * 16;
    float4 f[4];
#pragma unroll
    for (int i = 0; i < 4; i++) f[i] = *(const float4*)(p + i * 4);
    float* x = (float*)f;
    float mx = -__builtin_inff();
#pragma unroll
    for (int i = 0; i < 16; i++) mx = fmaxf(mx, x[i]);
    mx = wred_max(mx);
    float s = 0.f;
#pragma unroll
    for (int i = 0; i < 16; i++) { x[i] = __expf(x[i] - mx); s += x[i]; }
    s = wred_sum(s);
    const float sc = lamscale / s;
#pragma unroll
    for (int i = 0; i < 16; i++) x[i] *= sc;
#pragma unroll
    for (int i = 0; i < 4; i++) *(float4*)(p + i * 4) = f[i];
}

// out = LN(x + add) over 1024; x/add each f32 or bf16 (null-select); out bf16 or f32.
__global__ __launch_bounds__(256) void ln_residual(
    const float* __restrict__ xf, const u16* __restrict__ xbf,
    const float* __restrict__ addf, const u16* __restrict__ addbf,
    const float* __restrict__ w, const float* __restrict__ bb,
    u16* __restrict__ obf, float* __restrict__ of32)
{
    const int row = blockIdx.x;
    const int tid = threadIdx.x;
    const int lane = tid & 63, wid = tid >> 6;
    const long long base = (long long)row * 1024;
    float v[4];
    float s = 0.f;
#pragma unroll
    for (int i = 0; i < 4; i++) {
        const int c = tid * 4 + i;
        float x = xf ? xf[base + c] : bf2f(xbf[base + c]);
        x += addf ? addf[base + c] : bf2f(addbf[base + c]);
        v[i] = x; s += x;
    }
    __shared__ float red[8];
    s = wred_sum(s);
    if (lane == 0) red[wid] = s;
    __syncthreads();
    const float mu = (red[0] + red[1] + red[2] + red[3]) * (1.f / 1024.f);
    float ss = 0.f;
#pragma unroll
    for (int i = 0; i < 4; i++) { const float d = v[i] - mu; ss += d * d; }
    ss = wred_sum(ss);
    if (lane == 0) red[wid + 4] = ss;
    __syncthreads();
    const float var = (red[4] + red[5] + red[6] + red[7]) * (1.f / 1024.f);
    const float inv = rsqrtf(var + 1e-5f);
#pragma unroll
    for (int i = 0; i < 4; i++) {
        const int c = tid * 4 + i;
        const float o = (v[i] - mu) * inv * w[c] + bb[c];
        if (obf) obf[base + c] = f2bf(o);
        else     of32[base + c] = o;
    }
}

// ---------------------------------------------------------------------------
extern "C" void kernel_launch(void* const* d_in, const int* in_sizes, int n_in,
                              void* d_out, int out_size, void* d_ws, size_t ws_size,
                              hipStream_t stream)
{
    const float* X     = (const float*)d_in[0];   // [4,1024,1024]
    const int*   mask  = (const int*)d_in[1];     // [4,1024]
    const float* WQ1   = (const float*)d_in[2];
    const float* bQ1   = (const float*)d_in[3];
    const float* WK1   = (const float*)d_in[4];
    const float* bK1   = (const float*)d_in[5];
    const float* WV    = (const float*)d_in[6];
    const float* bV    = (const float*)d_in[7];
    const float* lnh_w = (const float*)d_in[8];
    const float* lnh_b = (const float*)d_in[9];
    const float* WO    = (const float*)d_in[10];  // [2048,1024]
    const float* bO    = (const float*)d_in[11];
    const float* ln1_w = (const float*)d_in[12];
    const float* ln1_b = (const float*)d_in[13];
    const float* ln2_w = (const float*)d_in[14];
    const float* ln2_b = (const float*)d_in[15];
    const float* W1    = (const float*)d_in[16];  // [1024,4096]
    const float* b1    = (const float*)d_in[17];
    const float* W2    = (const float*)d_in[18];  // [4096,1024]
    const float* b2    = (const float*)d_in[19];
    const float* lq1   = (const float*)d_in[20];
    const float* lk1   = (const float*)d_in[21];
    const float* lq2   = (const float*)d_in[22];
    const float* lk2   = (const float*)d_in[23];

    float* r2   = (float*)d_out;              // [4096,1024] f32, written LAST
    float* Aout = (float*)d_out + 4194304;    // [16,4,1024,1024] f32
    u16*   Vt   = (u16*)d_out;                // Vt scratch in r2 region (16 MB), dead before step 13

    // Workspace arena, 48 MB peak (byte offsets; lifetimes in step numbers):
    uint8_t* wp = (uint8_t*)d_ws;
    const size_t MB = 1024 * 1024;
    u16*   WqkT = (u16*)(wp + 0);          //  0..4   [1-3]
    u16*   WvT  = (u16*)(wp + 4 * MB);     //  4..8   [2-4]
    u16*   QK   = (u16*)(wp + 8 * MB);     //  8..24  [3-6]
    u16*   WOt  = (u16*)(wp + 0);          //  0..4   [5-10]
    u16*   Ocat = (u16*)(wp + 24 * MB);    // 24..40  [8-10]
    u16*   attnb= (u16*)(wp + 8 * MB);     //  8..16  [10-11]
    u16*   h1   = (u16*)(wp + 40 * MB);    // 40..48  [11-13]
    u16*   W1t  = (u16*)(wp + 24 * MB);    // 24..32  [11-12]
    u16*   W2t  = (u16*)(wp + 32 * MB);    // 32..40  [11-12]
    u16*   ff1c = (u16*)(wp + 0);          //  0..8   [12]
    float* ff2  = (float*)(wp + 8 * MB);   //  8..24  [12-13]
    (void)ws_size; (void)in_sizes; (void)n_in; (void)out_size;

    const long long Z = 0;
    const int NOSPLIT = 1 << 30;

    // 1-2. packs
    pack_wqkt<<<8192, 256, 0, stream>>>(WQ1, WK1, WqkT);
    pack_wvt<<<8192, 256, 0, stream>>>(WV, WvT);

    // 3. QK = X[4096,1024](f32) x WqkT^T + [bQ1|bK1] -> bf16 [4096,2048]
    gemm_bt<FLAG_OUT_BF16 | FLAG_BIAS, 1, 0><<<dim3(16, 32, 1), 256, 0, stream>>>(
        X, 1024, Z, Z, WqkT, 1024, Z, Z, QK, 2048, Z, Z,
        1024, 1, 1.f, bQ1, bK1, 1024, 0, nullptr, 0, nullptr, nullptr);

    // 4. Vt[h][b][v][t] = WvT[h] x X[b]^T(f32) + bV[h][v] -> bf16 (in r2 region)
    gemm_bt<FLAG_OUT_BF16 | FLAG_BIAS_ROW, 0, 1><<<dim3(8, 1, 64), 256, 0, stream>>>(
        WvT, 1024, 131072LL, Z, X, 1024, Z, 1048576LL,
        Vt, 1024, 524288LL, 131072LL,
        1024, 4, 1.f, bV, nullptr, NOSPLIT, 128, nullptr, 0, nullptr, nullptr);

    // 5. WOt pack (WqkT region, dead)
    transpose_bf<<<8192, 256, 0, stream>>>(WO, WOt, 11, 1024);

    // 6. scores: per (h,b) Q[1024,64] x K[1024,64]^T /32, mask -> f32 logits in A region
    gemm_bt<FLAG_SCALE | FLAG_MASK, 0, 0><<<dim3(8, 8, 64), 256, 0, stream>>>(
        QK, 2048, 64LL, 2097152LL, QK + 1024, 2048, 64LL, 2097152LL,
        Aout, 1024, 4194304LL, 1048576LL,
        64, 4, 0.03125f, nullptr, nullptr, NOSPLIT, 0, mask, 1024, nullptr, nullptr);

    // 7. softmax rows in place (f32), * (1-lam)
    softmax_rows<<<16384, 256, 0, stream>>>(Aout, lq1, lk1, lq2, lk2);

    // 8. PV + fused per-head LN: per (h,b) A[1024,1024](f32) x Vt[128,1024]^T
    //    -> LN(128), *(1-LAMBDA_INIT), scatter to Ocat[b][s][h*128+c] bf16
    gemm_bt<FLAG_LNH, 1, 0><<<dim3(1, 8, 64), 256, 0, stream>>>(
        Aout, 1024, 4194304LL, 1048576LL, Vt, 1024, 524288LL, 131072LL,
        Ocat, 2048, 128LL, 2097152LL,
        1024, 4, 1.f, nullptr, nullptr, NOSPLIT, 0, nullptr, 0, lnh_w, lnh_b);

    // 10. attn = Ocat[4096,2048] x WOt^T + bO -> bf16
    gemm_bt<FLAG_OUT_BF16 | FLAG_BIAS, 0, 0><<<dim3(8, 32, 1), 256, 0, stream>>>(
        Ocat, 2048, Z, Z, WOt, 2048, Z, Z, attnb, 1024, Z, Z,
        2048, 1, 1.f, bO, nullptr, NOSPLIT, 0, nullptr, 0, nullptr, nullptr);

    // 11. h1 = LN(X(f32) + attn(bf16)) -> bf16
    ln_residual<<<4096, 256, 0, stream>>>(X, nullptr, nullptr, attnb,
                                          ln1_w, ln1_b, h1, nullptr);

    // 11.5 W1t/W2t packs (Ocat region, dead after 10)
    transpose_bf<<<16384, 256, 0, stream>>>(W1, W1t, 10, 4096);
    transpose_bf<<<16384, 256, 0, stream>>>(W2, W2t, 12, 1024);

    // 12. FFN in 4 hidden-chunks of 1024
    for (int c = 0; c < 4; c++) {
        gemm_bt<FLAG_OUT_BF16 | FLAG_BIAS | FLAG_RELU, 0, 0><<<dim3(8, 32, 1), 256, 0, stream>>>(
            h1, 1024, Z, Z, W1t + (long long)c * 1048576, 1024, Z, Z,
            ff1c, 1024, Z, Z,
            1024, 1, 1.f, b1 + c * 1024, nullptr, NOSPLIT, 0, nullptr, 0, nullptr, nullptr);
        if (c == 0) {
            gemm_bt<FLAG_BIAS, 0, 0><<<dim3(8, 32, 1), 256, 0, stream>>>(
                ff1c, 1024, Z, Z, W2t + c * 1024, 4096, Z, Z, ff2, 1024, Z, Z,
                1024, 1, 1.f, b2, nullptr, NOSPLIT, 0, nullptr, 0, nullptr, nullptr);
        } else {
            gemm_bt<FLAG_ACCUM, 0, 0><<<dim3(8, 32, 1), 256, 0, stream>>>(
                ff1c, 1024, Z, Z, W2t + c * 1024, 4096, Z, Z, ff2, 1024, Z, Z,
                1024, 1, 1.f, nullptr, nullptr, NOSPLIT, 0, nullptr, 0, nullptr, nullptr);
        }
    }

    // 13. r2 = LN(h1(bf16) + ff2(f32)) -> f32 d_out (overwrites Vt scratch)
    ln_residual<<<4096, 256, 0, stream>>>(nullptr, h1, ff2, nullptr,
                                          ln2_w, ln2_b, nullptr, r2);
}